// Round 11
// baseline (103.434 us; speedup 1.0000x reference)
//
#include <hip/hip_runtime.h>

// SoftDiceLoss: predictions [B=8, C=16, H=512, W=512] fp32, targets [B,H,W] int32.
// out[b] = -(1/C) * sum_c (2*overlap[b,c] + 1) / (i_sum[b,c] + count[b,c] + 1)
//
// SINGLE fused kernel, 512 blocks = (8 batches x 64 slabs of 4096 pos) x 256 thr.
//  - tpack: thread's 16 targets packed 4b each in one u64; 5-VALU exact
//    nibble==c mask per class; count = popcount.
//  - Class streams read sequentially, 4-deep float4 bursts, with an explicit
//    ONE-CLASS-AHEAD double buffer (+16 VGPR) so the next burst is in flight
//    while the current class accumulates + DPP-reduces (in-loop, R7-style).
//    launch_bounds(256,4): grid gives 2 blocks/CU anyway; 128 VGPR = headroom,
//    no scratch (R9's 64-cap spilled 88 MB).
//  - partial[comp][block] in d_ws; last-done block (device-scope atomic on a
//    counter memset to 0 each launch) reduces 384 slab-columns via DPP and
//    writes out[0..7]. Fixed reduction order -> bitwise deterministic.

constexpr int  C_CLS   = 16;
constexpr long HW      = 512L * 512L;   // 262144 positions per (b,c) plane
constexpr int  BATCH   = 8;
constexpr int  SLAB    = 4096;          // positions per block
constexpr int  SLABS   = (int)(HW / SLAB);   // 64 per batch
constexpr int  NBLK    = BATCH * SLABS;      // 512
constexpr int  NPART   = 3 * C_CLS;          // 48 components

// Full wave64 sum via DPP (rocPRIM pattern). Result valid in lane 63.
__device__ __forceinline__ float wave_reduce_dpp(float x) {
    int t;
    t = __builtin_amdgcn_update_dpp(0, __float_as_int(x), 0x111, 0xf, 0xf, true); // row_shr:1
    x += __int_as_float(t);
    t = __builtin_amdgcn_update_dpp(0, __float_as_int(x), 0x112, 0xf, 0xf, true); // row_shr:2
    x += __int_as_float(t);
    t = __builtin_amdgcn_update_dpp(0, __float_as_int(x), 0x114, 0xf, 0xf, true); // row_shr:4
    x += __int_as_float(t);
    t = __builtin_amdgcn_update_dpp(0, __float_as_int(x), 0x118, 0xf, 0xf, true); // row_shr:8
    x += __int_as_float(t);
    t = __builtin_amdgcn_update_dpp(0, __float_as_int(x), 0x142, 0xa, 0xf, true); // row_bcast:15
    x += __int_as_float(t);
    t = __builtin_amdgcn_update_dpp(0, __float_as_int(x), 0x143, 0xc, 0xf, true); // row_bcast:31
    x += __int_as_float(t);
    return x;
}

__global__ __launch_bounds__(256, 4)
void dice_fused_kernel(const float* __restrict__ pred,
                       const int*   __restrict__ tgt,
                       float*       __restrict__ partial,
                       unsigned*    __restrict__ ctr,
                       float*       __restrict__ out) {
    const int g    = blockIdx.x;
    const int slab = g & (SLABS - 1);
    const int b    = g >> 6;
    const int tid  = threadIdx.x;
    const int lane = tid & 63;
    const int wv   = tid >> 6;

    const long sbase = (long)slab * SLAB;
    const int* tb = tgt + (long)b * HW + sbase;

    // pack this thread's 16 target values into one u64 (4 bits each)
    unsigned long long tpack = 0ull;
#pragma unroll
    for (int j = 0; j < 4; ++j) {
        const int4 tv = *reinterpret_cast<const int4*>(tb + j * 1024 + tid * 4);
        const unsigned nib = (unsigned)tv.x | ((unsigned)tv.y << 4)
                           | ((unsigned)tv.z << 8) | ((unsigned)tv.w << 12);
        tpack |= (unsigned long long)nib << (16 * j);
    }

    const float* pb = pred + (long)b * C_CLS * HW + sbase + tid * 4;

    __shared__ float sm[4][NPART];

    // prefetch class 0 burst
    float4 nA0 = *reinterpret_cast<const float4*>(pb + 0 * 1024);
    float4 nA1 = *reinterpret_cast<const float4*>(pb + 1 * 1024);
    float4 nA2 = *reinterpret_cast<const float4*>(pb + 2 * 1024);
    float4 nA3 = *reinterpret_cast<const float4*>(pb + 3 * 1024);

#pragma unroll
    for (int c = 0; c < C_CLS; ++c) {
        const float4 p0 = nA0, p1 = nA1, p2 = nA2, p3 = nA3;
        if (c < C_CLS - 1) {          // issue next class's burst NOW
            const float* nb = pb + (long)(c + 1) * HW;
            nA0 = *reinterpret_cast<const float4*>(nb + 0 * 1024);
            nA1 = *reinterpret_cast<const float4*>(nb + 1 * 1024);
            nA2 = *reinterpret_cast<const float4*>(nb + 2 * 1024);
            nA3 = *reinterpret_cast<const float4*>(nb + 3 * 1024);
        }

        // exact per-nibble (t==c) mask: bit 4i of m = match at position i
        unsigned long long x = tpack ^ ((unsigned long long)c * 0x1111111111111111ull);
        x |= x >> 2;
        x |= x >> 1;
        const unsigned long long m = ~x & 0x1111111111111111ull;

        float is = 0.f, o = 0.f;
        const unsigned mb0 = (unsigned)m;
        is += (p0.x + p0.y) + (p0.z + p0.w);
        o  += ((mb0 & 0x0001u) ? p0.x : 0.f) + ((mb0 & 0x0010u) ? p0.y : 0.f)
            + ((mb0 & 0x0100u) ? p0.z : 0.f) + ((mb0 & 0x1000u) ? p0.w : 0.f);
        const unsigned mb1 = (unsigned)(m >> 16);
        is += (p1.x + p1.y) + (p1.z + p1.w);
        o  += ((mb1 & 0x0001u) ? p1.x : 0.f) + ((mb1 & 0x0010u) ? p1.y : 0.f)
            + ((mb1 & 0x0100u) ? p1.z : 0.f) + ((mb1 & 0x1000u) ? p1.w : 0.f);
        const unsigned mb2 = (unsigned)(m >> 32);
        is += (p2.x + p2.y) + (p2.z + p2.w);
        o  += ((mb2 & 0x0001u) ? p2.x : 0.f) + ((mb2 & 0x0010u) ? p2.y : 0.f)
            + ((mb2 & 0x0100u) ? p2.z : 0.f) + ((mb2 & 0x1000u) ? p2.w : 0.f);
        const unsigned mb3 = (unsigned)(m >> 48);
        is += (p3.x + p3.y) + (p3.z + p3.w);
        o  += ((mb3 & 0x0001u) ? p3.x : 0.f) + ((mb3 & 0x0010u) ? p3.y : 0.f)
            + ((mb3 & 0x0100u) ? p3.z : 0.f) + ((mb3 & 0x1000u) ? p3.w : 0.f);

        // in-loop DPP reduce (VALU work overlaps the in-flight next burst)
        is = wave_reduce_dpp(is);
        o  = wave_reduce_dpp(o);
        float cn = wave_reduce_dpp((float)__popcll(m));
        if (lane == 63) {
            sm[wv][c * 3 + 0] = is;
            sm[wv][c * 3 + 1] = o;
            sm[wv][c * 3 + 2] = cn;
        }
    }

    __syncthreads();
    if (tid < NPART) {
        partial[(long)tid * NBLK + g] =
            (sm[0][tid] + sm[1][tid]) + (sm[2][tid] + sm[3][tid]);
    }
    __threadfence();                       // publish partials device-wide
    __syncthreads();

    __shared__ bool lastf;
    if (tid == 0) lastf = (atomicAdd(ctr, 1u) == (unsigned)(NBLK - 1));
    __syncthreads();
    if (!lastf) return;

    // ---- last-done block: final reduction ----
    __threadfence();                       // acquire all partials

    __shared__ float tot[BATCH][NPART];
    // wave wv handles batches 2*wv and 2*wv+1; 64 slab-columns per batch
#pragma unroll
    for (int i = 0; i < 2; ++i) {
        const int bb = wv * 2 + i;
#pragma unroll
        for (int k = 0; k < NPART; ++k) {
            float v = partial[(long)k * NBLK + bb * SLABS + lane];
            v = wave_reduce_dpp(v);
            if (lane == 63) tot[bb][k] = v;
        }
    }
    __syncthreads();

    if (tid < BATCH) {
        float s = 0.f;
#pragma unroll
        for (int c = 0; c < C_CLS; ++c) {
            const float is = tot[tid][c * 3 + 0];
            const float o  = tot[tid][c * 3 + 1];
            const float cn = tot[tid][c * 3 + 2];
            s += (2.f * o + 1.f) / (is + cn + 1.f);
        }
        out[tid] = -s * (1.f / (float)C_CLS);
    }
}

extern "C" void kernel_launch(void* const* d_in, const int* in_sizes, int n_in,
                              void* d_out, int out_size, void* d_ws, size_t ws_size,
                              hipStream_t stream) {
    const float* pred = (const float*)d_in[0];
    const int*   tgt  = (const int*)d_in[1];
    float*       out  = (float*)d_out;

    float*    partial = (float*)d_ws;                       // 48*512*4 = 98304 B
    unsigned* ctr     = (unsigned*)((char*)d_ws + (size_t)NPART * NBLK * 4);

    hipMemsetAsync(ctr, 0, sizeof(unsigned), stream);       // deterministic re-arm
    dice_fused_kernel<<<NBLK, 256, 0, stream>>>(pred, tgt, partial, ctr, out);
}